// Round 13
// baseline (299.080 us; speedup 1.0000x reference)
//
#include <hip/hip_runtime.h>
#include <hip/hip_bf16.h>
#include <math.h>

// GRACE-style graph contrastive loss, MI355X (gfx950).
// R13: 16 -> 10 ops. setup2_k = wt(4) + hist + mlp12(inline fp32 weight cvt);
// gg_k = gather32 + g34 (same block geometry as standalone gather32 -> no
// occupancy loss, ax stays in LDS); pn_k = proj1+proj2+norm with PAIR-ROW blocks
// (rows i and i+8192 in one block -> bdot/norm/fp8-quant in-block; kills t2 + z
// roundtrip, 22MB). gather128 standalone (fusing would cut its occupancy 4x).
// gram3 (53us, 5 variants failed to beat) and rloss untouched.

#define NROWS 8192
#define MROWS 16384
#define NEDGE 262144

typedef __attribute__((ext_vector_type(8))) short bf16x8;
typedef __attribute__((ext_vector_type(4))) float f32x4;
typedef __attribute__((ext_vector_type(2))) float f32x2;
typedef long long i64;

__device__ __forceinline__ short f2bf(float f){
  union { float f; unsigned u; } cv; cv.f = f;
  unsigned u = cv.u;
  unsigned r = (u + 0x7fffu + ((u >> 16) & 1u)) >> 16;  // RNE; inputs finite
  return (short)r;
}
__device__ __forceinline__ f32x4 mfma16(bf16x8 a, bf16x8 b, f32x4 c){
  return __builtin_amdgcn_mfma_f32_16x16x32_bf16(a, b, c, 0, 0, 0);
}
__device__ __forceinline__ float fexp2(float x){
#if __has_builtin(__builtin_amdgcn_exp2f)
  return __builtin_amdgcn_exp2f(x);
#else
  return exp2f(x);
#endif
}

// ---- fp8 e4m3fn pack (RNE) ----
__device__ unsigned char f2e4m3_sw(float f){
  float a = fabsf(f);
  unsigned s = (__float_as_uint(f)>>24)&0x80u;
  if (!(a>0.f)) return (unsigned char)s;
  if (a>448.f) a=448.f;
  int e; frexpf(a,&e);
  int eff=e-1;
  unsigned code;
  if (eff<-6){
    float q=rintf(a*512.f);
    code=(unsigned)q; if(code>7)code=7;
  } else {
    float q=rintf(a*exp2f((float)(3-eff)));
    unsigned mant=(unsigned)q;
    if(mant>=16){mant=8;eff++;}
    if(eff>8) return (unsigned char)(s|0x7e);
    code=((unsigned)(eff+7)<<3)|(mant-8);
  }
  return (unsigned char)(s|code);
}
__device__ __forceinline__ unsigned short pack2fp8(float a, float b){
#if __has_builtin(__builtin_amdgcn_cvt_pk_fp8_f32)
  int v = __builtin_amdgcn_cvt_pk_fp8_f32(a, b, 0, false);
  return (unsigned short)(v & 0xffff);
#else
  return (unsigned short)((unsigned)f2e4m3_sw(a) | ((unsigned)f2e4m3_sw(b)<<8));
#endif
}

// ---- setup2: weight transpose (4 weights) | degree hist | fused MLP layer1 ----
struct WtArgs {
  const float* src[4];
  short* dst[4];
  int K[4], N[4];
  int off[5];
  int nwt;
};
__global__ __launch_bounds__(256) void setup2_k(WtArgs a,
    const int* __restrict__ ei1, const int* __restrict__ ei2,
    int* __restrict__ deg1, int* __restrict__ deg2,
    const float* __restrict__ F0, const float* __restrict__ F1,
    const float* __restrict__ Wa, const float* __restrict__ ba,
    const float* __restrict__ Wb, const float* __restrict__ bb,
    short* __restrict__ xb){
  __shared__ short a1s[64*72];
  int b = blockIdx.x;
  if (b < a.nwt){
    int i = b*256 + threadIdx.x;
    if (i >= a.off[4]) return;
    int s = 0;
    #pragma unroll
    for (int j=1;j<4;j++) if (i >= a.off[j]) s=j;
    int l = i - a.off[s];
    int K=a.K[s], N=a.N[s];
    int k=l/N, n=l-k*N;
    a.dst[s][(long)n*K+k] = f2bf(a.src[s][l]);
    return;
  }
  if (b < a.nwt + 2*(NEDGE/256)){
    int hb = b - a.nwt;
    const int* ei = (hb < NEDGE/256) ? ei1 : ei2;
    int* deg = (hb < NEDGE/256) ? deg1 : deg2;
    int e = (hb % (NEDGE/256))*256 + threadIdx.x;
    atomicAdd(&deg[ei[e]], 1);
    return;
  }
  // ---- fused MLP: xb[M,32] = (relu(feat@Wa + ba))@Wb + bb ----
  const int mb = b - (a.nwt + 2*(NEDGE/256));
  const int tid = threadIdx.x;
  const int wave = tid>>6, lane = tid&63, quad = lane>>4, cl = lane&15;
  const int m0 = mb*64;
  const int wno = wave*16;     // stage1: NT=1, 16-col slab
  f32x4 zero = {0.f,0.f,0.f,0.f};
  f32x4 acc[4];
  #pragma unroll
  for (int i=0;i<4;i++) acc[i]=zero;
  #pragma unroll
  for (int kc=0;kc<16;kc++){
    const int ko = kc*32 + quad*8;
    bf16x8 av[4], bv;
    #pragma unroll
    for (int mt=0;mt<4;mt++){
      int row = m0 + mt*16 + cl;
      const float* ar = (row < NROWS) ? (F0 + (long)row*512 + ko)
                                      : (F1 + (long)(row-NROWS)*512 + ko);
      float4 f0 = *(const float4*)ar;
      float4 f1 = *(const float4*)(ar+4);
      bf16x8 t;
      t[0]=f2bf(f0.x); t[1]=f2bf(f0.y); t[2]=f2bf(f0.z); t[3]=f2bf(f0.w);
      t[4]=f2bf(f1.x); t[5]=f2bf(f1.y); t[6]=f2bf(f1.z); t[7]=f2bf(f1.w);
      av[mt]=t;
    }
    #pragma unroll
    for (int j=0;j<8;j++) bv[j] = f2bf(Wa[(long)(ko+j)*64 + wno + cl]);  // inline cvt
    #pragma unroll
    for (int mt=0;mt<4;mt++) acc[mt] = mfma16(av[mt], bv, acc[mt]);
  }
  {
    int col = wno + cl;
    float bva = ba[col];
    #pragma unroll
    for (int mt=0;mt<4;mt++)
      #pragma unroll
      for (int r=0;r<4;r++)
        a1s[(mt*16 + quad*4 + r)*72 + col] = f2bf(fmaxf(acc[mt][r] + bva, 0.f));
  }
  __syncthreads();
  const int wmo = wave*16;     // stage2: 16-row strip, full 32 cols, K=64
  f32x4 acc2[2] = {zero, zero};
  #pragma unroll
  for (int kc=0;kc<2;kc++){
    const int ko = kc*32 + quad*8;
    bf16x8 av = *(const bf16x8*)&a1s[(wmo+cl)*72 + ko];
    #pragma unroll
    for (int nt=0;nt<2;nt++){
      bf16x8 bv;
      #pragma unroll
      for (int j=0;j<8;j++) bv[j] = f2bf(Wb[(long)(ko+j)*32 + nt*16 + cl]);
      acc2[nt] = mfma16(av, bv, acc2[nt]);
    }
  }
  #pragma unroll
  for (int nt=0;nt<2;nt++){
    int col = nt*16 + cl;
    float bvb = bb[col];
    #pragma unroll
    for (int r=0;r<4;r++)
      xb[(long)(m0 + wmo + quad*4 + r)*32 + col] = f2bf(acc2[nt][r] + bvb);
  }
}

// ---- CSR build ----
__global__ void scan2_k(const int* __restrict__ deg1, int* __restrict__ rs1, int* __restrict__ cur1,
                        const int* __restrict__ deg2, int* __restrict__ rs2, int* __restrict__ cur2){
  const int* deg = blockIdx.x ? deg2 : deg1;
  int* rowstart = blockIdx.x ? rs2 : rs1;
  int* cursor = blockIdx.x ? cur2 : cur1;
  __shared__ int csum[256];
  __shared__ int base[257];
  int t = threadIdx.x;
  int loc[32];
  int s = 0;
  for (int j=0;j<32;j++){ int d = deg[t*32+j]; loc[j] = s; s += d; }
  csum[t] = s;
  __syncthreads();
  if (t==0){ int a=0; for (int i=0;i<256;i++){ base[i]=a; a+=csum[i]; } base[256]=a; }
  __syncthreads();
  for (int j=0;j<32;j++){ int v = base[t] + loc[j]; rowstart[t*32+j]=v; cursor[t*32+j]=v; }
  if (t==0) rowstart[NROWS] = base[256];
}
__global__ void fill2_k(const int* __restrict__ ei1, const float* __restrict__ w1, int* __restrict__ cur1,
                        int* __restrict__ ecol1, float* __restrict__ ew1,
                        const int* __restrict__ ei2, const float* __restrict__ w2, int* __restrict__ cur2,
                        int* __restrict__ ecol2, float* __restrict__ ew2){
  int b = blockIdx.x;
  bool g2 = (b >= NEDGE/256);
  const int* ei = g2 ? ei2 : ei1;
  const float* w = g2 ? w2 : w1;
  int* cursor = g2 ? cur2 : cur1;
  int* ecol = g2 ? ecol2 : ecol1;
  float* ew = g2 ? ew2 : ew1;
  int e = (b % (NEDGE/256))*256 + threadIdx.x;
  int r = ei[e];
  int p = atomicAdd(&cursor[r], 1);
  ecol[p] = ei[NEDGE + e];
  ew[p] = w[e];
}

// ---- gather helper ----
__device__ __forceinline__ void acc8(float* acc, int4 v, float f){
  const unsigned* u = (const unsigned*)&v;
  #pragma unroll
  for (int i=0;i<4;i++){
    union{unsigned x; float y;} lo, hi;
    lo.x = u[i] << 16;
    hi.x = u[i] & 0xffff0000u;
    acc[2*i]   = fmaf(f, lo.y, acc[2*i]);
    acc[2*i+1] = fmaf(f, hi.y, acc[2*i+1]);
  }
}
template<int C>
__device__ __forceinline__ void gather_row(float* acc, const short* sb,
                                           const int* ec, const float* w, int s, int e){
  int k = s;
  for (; k+16 <= e; k+=16){
    int c[16]; float f[16]; int4 v[16];
    #pragma unroll
    for (int u=0;u<16;u++){ c[u]=ec[k+u]; f[u]=w[k+u]; }
    #pragma unroll
    for (int u=0;u<16;u++) v[u] = *(const int4*)(sb + (long)c[u]*C);
    #pragma unroll
    for (int u=0;u<16;u++) acc8(acc, v[u], f[u]);
  }
  for (; k+4 <= e; k+=4){
    int c0=ec[k],c1=ec[k+1],c2=ec[k+2],c3=ec[k+3];
    float f0=w[k],f1=w[k+1],f2=w[k+2],f3=w[k+3];
    int4 v0 = *(const int4*)(sb + (long)c0*C);
    int4 v1 = *(const int4*)(sb + (long)c1*C);
    int4 v2 = *(const int4*)(sb + (long)c2*C);
    int4 v3 = *(const int4*)(sb + (long)c3*C);
    acc8(acc,v0,f0); acc8(acc,v1,f1); acc8(acc,v2,f2); acc8(acc,v3,f3);
  }
  for (; k < e; k++){
    int4 v0 = *(const int4*)(sb + (long)ec[k]*C);
    acc8(acc,v0,w[k]);
  }
}

// ---- standalone gather (layer-2 aggregation, C=128, bias) ----
template<int C, bool RELU, bool HASB>
__global__ __launch_bounds__(256) void gather_k(const short* __restrict__ sup,
    const int* __restrict__ rs1, const int* __restrict__ ec1, const float* __restrict__ w1,
    const int* __restrict__ rs2, const int* __restrict__ ec2, const float* __restrict__ w2,
    const float* __restrict__ bias, short* __restrict__ out){
  constexpr int G = C/8;
  const int g = threadIdx.x % G;
  const int sub = threadIdx.x / G;
  const int row = blockIdx.x*(256/G) + sub;
  const int* rs; const int* ec; const float* w; int soff, lr;
  if (row < NROWS){ rs=rs1; ec=ec1; w=w1; soff=0; lr=row; }
  else            { rs=rs2; ec=ec2; w=w2; soff=NROWS; lr=row-NROWS; }
  const short* sb = sup + (long)soff*C + g*8;
  float acc[8];
  #pragma unroll
  for (int j=0;j<8;j++) acc[j] = HASB ? bias[g*8+j] : 0.f;
  gather_row<C>(acc, sb, ec, w, rs[lr], rs[lr+1]);
  int4 ov;
  unsigned* ou = (unsigned*)&ov;
  #pragma unroll
  for (int i=0;i<4;i++){
    float a0 = acc[2*i], a1 = acc[2*i+1];
    if (RELU){ a0 = fmaxf(a0,0.f); a1 = fmaxf(a1,0.f); }
    ou[i] = (unsigned)(unsigned short)f2bf(a0) | ((unsigned)(unsigned short)f2bf(a1)<<16);
  }
  *(int4*)(out + (long)row*C + g*8) = ov;
}

// ---- gg_k: gather32 (adj@xb -> LDS) + g34 (relu(ax@Wg1+bg1)@Wg2 -> s2) ----
__global__ __launch_bounds__(256) void gg_k(const short* __restrict__ xb,
    const int* __restrict__ rs1, const int* __restrict__ ec1, const float* __restrict__ w1,
    const int* __restrict__ rs2, const int* __restrict__ ec2, const float* __restrict__ w2,
    const short* __restrict__ Wg1, const float* __restrict__ bg1,
    const short* __restrict__ Wg2, short* __restrict__ s2){
  __shared__ short axs[64*40];    // gathered ax tile (pad 8)
  __shared__ short hbs[64*264];   // relu(ax@Wg1+b) tile (pad 8)
  const int tid = threadIdx.x;
  const int m0 = blockIdx.x*64;
  {
    // phase 1: gather 64 rows of adj@xb into LDS (same geometry as old gather32)
    const int g = tid & 3, sub = tid >> 2;
    const int row = m0 + sub;
    const int* rs; const int* ec; const float* w; int soff, lr;
    if (row < NROWS){ rs=rs1; ec=ec1; w=w1; soff=0; lr=row; }
    else            { rs=rs2; ec=ec2; w=w2; soff=NROWS; lr=row-NROWS; }
    const short* sb = xb + (long)soff*32 + g*8;
    float acc[8];
    #pragma unroll
    for (int j=0;j<8;j++) acc[j] = 0.f;
    gather_row<32>(acc, sb, ec, w, rs[lr], rs[lr+1]);
    int4 ov;
    unsigned* ou = (unsigned*)&ov;
    #pragma unroll
    for (int i=0;i<4;i++)
      ou[i] = (unsigned)(unsigned short)f2bf(acc[2*i]) | ((unsigned)(unsigned short)f2bf(acc[2*i+1])<<16);
    *(int4*)&axs[sub*40 + g*8] = ov;
  }
  __syncthreads();
  const int wave = tid>>6, lane = tid&63, quad = lane>>4, cl = lane&15;
  f32x4 zero = {0.f,0.f,0.f,0.f};
  {
    // phase 2: stage1 NN=256 K=32
    const int wno = wave*64;
    f32x4 acc[4][4];
    #pragma unroll
    for (int i=0;i<4;i++)
      #pragma unroll
      for (int j=0;j<4;j++) acc[i][j]=zero;
    const int ko = quad*8;
    bf16x8 a[4], b[4];
    #pragma unroll
    for (int mt=0;mt<4;mt++)
      a[mt] = *(const bf16x8*)&axs[(mt*16+cl)*40 + ko];
    #pragma unroll
    for (int nt=0;nt<4;nt++)
      b[nt] = *(const bf16x8*)(Wg1 + (long)(wno + nt*16 + cl)*32 + ko);
    #pragma unroll
    for (int mt=0;mt<4;mt++)
      #pragma unroll
      for (int nt=0;nt<4;nt++)
        acc[mt][nt] = mfma16(a[mt], b[nt], acc[mt][nt]);
    #pragma unroll
    for (int nt=0;nt<4;nt++){
      int col = wno + nt*16 + cl;
      float bv = bg1[col];
      #pragma unroll
      for (int mt=0;mt<4;mt++)
        #pragma unroll
        for (int r=0;r<4;r++)
          hbs[(mt*16 + quad*4 + r)*264 + col] = f2bf(fmaxf(acc[mt][nt][r] + bv, 0.f));
    }
  }
  __syncthreads();
  {
    // phase 3: stage2 NN=128 K=256
    const int wno = wave*32;
    f32x4 acc[4][2];
    #pragma unroll
    for (int i=0;i<4;i++){ acc[i][0]=zero; acc[i][1]=zero; }
    #pragma unroll
    for (int kc=0;kc<8;kc++){
      const int ko = kc*32 + quad*8;
      bf16x8 a[4], b[2];
      #pragma unroll
      for (int mt=0;mt<4;mt++)
        a[mt] = *(const bf16x8*)&hbs[(mt*16+cl)*264 + ko];
      #pragma unroll
      for (int nt=0;nt<2;nt++)
        b[nt] = *(const bf16x8*)(Wg2 + (long)(wno + nt*16 + cl)*256 + ko);
      #pragma unroll
      for (int mt=0;mt<4;mt++)
        #pragma unroll
        for (int nt=0;nt<2;nt++)
          acc[mt][nt] = mfma16(a[mt], b[nt], acc[mt][nt]);
    }
    #pragma unroll
    for (int mt=0;mt<4;mt++)
      #pragma unroll
      for (int nt=0;nt<2;nt++){
        int col = wno + nt*16 + cl;
        #pragma unroll
        for (int r=0;r<4;r++)
          s2[(long)(m0 + mt*16 + quad*4 + r)*128 + col] = f2bf(acc[mt][nt][r]);
      }
  }
}

// ---- pn_k: proj1(elu) + proj2 + normalize + fp8-quantize, PAIR-ROW blocks ----
// Block b handles local rows lr in [0,64): lr<32 -> view1 row b*32+lr,
// lr>=32 -> view2 row 8192+b*32+(lr-32). bdot computed in-block.
__global__ __launch_bounds__(256) void pn_k(const short* __restrict__ hh,
    const short* __restrict__ Wf1, const float* __restrict__ bf1,
    const short* __restrict__ Wf2, const float* __restrict__ bf2,
    unsigned short* __restrict__ Zf, float* __restrict__ bdot){
  __shared__ short t2s[64*72];
  __shared__ float zs[64*132];
  __shared__ float sp[4][64];
  __shared__ float dp[4][32];
  __shared__ float rnS[64];
  const float SQKE = 1.6986436f;   // sqrt(2*log2(e))
  const int tid = threadIdx.x;
  const int wave = tid>>6, lane = tid&63, quad = lane>>4, cl = lane&15;
  const int m0h = blockIdx.x*32;
  f32x4 zero = {0.f,0.f,0.f,0.f};
  {
    // proj1: NN=64, K=128, elu -> t2s
    const int wno = wave*16;
    f32x4 acc[4];
    #pragma unroll
    for (int i=0;i<4;i++) acc[i]=zero;
    #pragma unroll
    for (int kc=0;kc<4;kc++){
      const int ko = kc*32 + quad*8;
      bf16x8 a[4], b;
      #pragma unroll
      for (int mt=0;mt<4;mt++){
        int lr = mt*16 + cl;
        int grow = (lr < 32) ? (m0h + lr) : (NROWS + m0h + lr - 32);
        a[mt] = *(const bf16x8*)(hh + (long)grow*128 + ko);
      }
      b = *(const bf16x8*)(Wf1 + (long)(wno + cl)*128 + ko);
      #pragma unroll
      for (int mt=0;mt<4;mt++) acc[mt] = mfma16(a[mt], b, acc[mt]);
    }
    int col = wno + cl;
    float bv = bf1[col];
    #pragma unroll
    for (int mt=0;mt<4;mt++)
      #pragma unroll
      for (int r=0;r<4;r++){
        float v = acc[mt][r] + bv;
        v = (v > 0.f) ? v : expm1f(v);
        t2s[(mt*16 + quad*4 + r)*72 + col] = f2bf(v);
      }
  }
  __syncthreads();
  {
    // proj2: NN=128, K=64 -> zs (fp32)
    const int wno = wave*32;
    f32x4 acc[4][2];
    #pragma unroll
    for (int i=0;i<4;i++){ acc[i][0]=zero; acc[i][1]=zero; }
    #pragma unroll
    for (int kc=0;kc<2;kc++){
      const int ko = kc*32 + quad*8;
      bf16x8 a[4], b[2];
      #pragma unroll
      for (int mt=0;mt<4;mt++)
        a[mt] = *(const bf16x8*)&t2s[(mt*16+cl)*72 + ko];
      #pragma unroll
      for (int nt=0;nt<2;nt++)
        b[nt] = *(const bf16x8*)(Wf2 + (long)(wno + nt*16 + cl)*64 + ko);
      #pragma unroll
      for (int mt=0;mt<4;mt++)
        #pragma unroll
        for (int nt=0;nt<2;nt++)
          acc[mt][nt] = mfma16(a[mt], b[nt], acc[mt][nt]);
    }
    #pragma unroll
    for (int mt=0;mt<4;mt++)
      #pragma unroll
      for (int nt=0;nt<2;nt++){
        int col = wno + nt*16 + cl;
        float bv = bf2[col];
        #pragma unroll
        for (int r=0;r<4;r++)
          zs[(mt*16 + quad*4 + r)*132 + col] = acc[mt][nt][r] + bv;
      }
  }
  __syncthreads();
  {
    // per-row ssq + pair-dot partials (4 col-quarters)
    int row = tid & 63, qtr = tid >> 6;
    const float* zr = &zs[row*132 + qtr*32];
    float s = 0.f;
    #pragma unroll 8
    for (int c=0;c<32;c++) s += zr[c]*zr[c];
    sp[qtr][row] = s;
    if (row < 32){
      const float* zb_ = &zs[(row+32)*132 + qtr*32];
      float d = 0.f;
      #pragma unroll 8
      for (int c=0;c<32;c++) d += zr[c]*zb_[c];
      dp[qtr][row] = d;
    }
  }
  __syncthreads();
  if (tid < 64){
    float ssq = sp[0][tid]+sp[1][tid]+sp[2][tid]+sp[3][tid];
    rnS[tid] = 1.f / fmaxf(sqrtf(ssq), 1e-12f);
  }
  __syncthreads();
  if (tid < 32){
    float dot = dp[0][tid]+dp[1][tid]+dp[2][tid]+dp[3][tid];
    bdot[m0h + tid] = dot * rnS[tid] * rnS[tid+32];
  }
  {
    // fp8*sqrt(KE) quantize into MFMA-fragment-order Zf (same mapping as norm_k)
    int lr = tid >> 2;
    int grow = (lr < 32) ? (m0h + lr) : (NROWS + m0h + lr - 32);
    float s = rnS[lr] * SQKE;
    int p0 = (tid & 3)*16;
    #pragma unroll
    for (int pp=0;pp<16;pp++){
      int p = p0 + pp;
      int d = p>>1, h = p&1, kc = d>>3, q = (d>>1)&3, j4 = d&1;
      long o = ((long)(grow>>4)*512 + kc*128 + j4 + ((grow&15)+16*q)*2)*2 + h;
      Zf[o] = pack2fp8(zs[lr*132 + 2*p]*s, zs[lr*132 + 2*p + 1]*s);
    }
  }
}

// ---- LDS-free symmetric exp-Gram partials (proven 53us; do not touch).
__global__ __launch_bounds__(256,4) void gram3_k(const unsigned char* __restrict__ Zf,
                                                 float* __restrict__ P){
  __shared__ float srow[4][64];
  __shared__ float scol[4][64];
  const int wave = threadIdx.x>>6, lane = threadIdx.x&63;
  const int t = blockIdx.x*4 + wave;           // UT tile index, T=256
  int ti = (int)((513.0f - sqrtf(513.0f*513.0f - 8.0f*(float)t))*0.5f);
  while ((ti+1)*256 - ((ti+1)*ti)/2 <= t) ti++;
  while (ti*256 - (ti*(ti-1))/2 > t) ti--;
  const int tj = ti + (t - (ti*256 - (ti*(ti-1))/2));
  const unsigned char* za = Zf + (long)ti*16*512 + lane*8;
  const unsigned char* zb = Zf + (long)tj*16*512 + lane*8;

  f32x4 zero = {0.f,0.f,0.f,0.f};
  f32x4 acc[4][4];
  #pragma unroll
  for (int i=0;i<4;i++)
    #pragma unroll
    for (int j=0;j<4;j++) acc[i][j]=zero;

  i64 aA[4], bA[4], aB[4], bB[4];
  #pragma unroll
  for (int x=0;x<4;x++){
    aA[x] = *(const i64*)(za + (x*4+0)*512);
    bA[x] = *(const i64*)(zb + (x*4+0)*512);
  }
  #pragma unroll
  for (int kc=0;kc<4;kc++){
    i64* ac = (kc&1) ? aB : aA;
    i64* bc = (kc&1) ? bB : bA;
    i64* an = (kc&1) ? aA : aB;
    i64* bn = (kc&1) ? bA : bB;
    if (kc<3){
      #pragma unroll
      for (int x=0;x<4;x++){
        an[x] = *(const i64*)(za + (x*4+kc+1)*512);
        bn[x] = *(const i64*)(zb + (x*4+kc+1)*512);
      }
    }
    #pragma unroll
    for (int mt=0;mt<4;mt++)
      #pragma unroll
      for (int nt=0;nt<4;nt++)
        acc[mt][nt] = __builtin_amdgcn_mfma_f32_16x16x32_fp8_fp8(ac[mt], bc[nt], acc[mt][nt], 0, 0, 0);
  }

  const int quad = lane>>4, cl = lane&15;
  f32x2 z2 = {0.f,0.f};
  f32x2 rs01[4] = {z2,z2,z2,z2}, rs23[4] = {z2,z2,z2,z2};
  f32x2 cs[4] = {z2,z2,z2,z2};
  #pragma unroll
  for (int mt=0;mt<4;mt++){
    #pragma unroll
    for (int nt=0;nt<4;nt++){
      f32x4 v = acc[mt][nt];
      float e0 = fexp2(v[0]), e1 = fexp2(v[1]);
      float e2 = fexp2(v[2]), e3 = fexp2(v[3]);
      f32x2 p01 = {e0,e1}, p23 = {e2,e3};
      rs01[mt] += p01; rs23[mt] += p23;
      cs[nt] += p01; cs[nt] += p23;
    }
  }
  #pragma unroll
  for (int mt=0;mt<4;mt++){
    union{f32x2 v; double d;} u0, u1;
    u0.v = rs01[mt]; u1.v = rs23[mt];
    #pragma unroll
    for (int m=1;m<16;m<<=1){
      union{double d; f32x2 v;} o0, o1;
      o0.d = __shfl_xor(u0.d, m); o1.d = __shfl_xor(u1.d, m);
      u0.v += o0.v; u1.v += o1.v;
    }
    if (cl==0){
      f32x4 rv = {u0.v.x, u0.v.y, u1.v.x, u1.v.y};
      *(f32x4*)&srow[wave][mt*16 + quad*4] = rv;
    }
  }
  __threadfence_block();
  P[((long)ti*256 + tj)*64 + lane] = srow[wave][lane];
  if (ti != tj){
    #pragma unroll
    for (int nt=0;nt<4;nt++){
      float s = cs[nt].x + cs[nt].y;
      s += __shfl_xor(s,16); s += __shfl_xor(s,32);
      if (quad==0) scol[wave][nt*16 + cl] = s;
    }
    __threadfence_block();
    P[((long)tj*256 + ti)*64 + lane] = scol[wave][lane];
  }
}

// ---- fused final reduce + loss ----
__global__ void rloss_k(const float* __restrict__ P, const float* __restrict__ bdot,
                        float* __restrict__ out){
  __shared__ float red[256];
  const float E2 = 7.3890560989306495f;  // exp(2) = diag(refl)
  int t = threadIdx.x;
  int i = blockIdx.x*256 + t;            // 0..8191
  int j = i + NROWS;
  const float* p1 = P + (long)(i>>6)*256*64 + (i&63);
  const float* p2 = P + (long)(j>>6)*256*64 + (j&63);
  float s1 = 0.f, s2 = 0.f;
  #pragma unroll 8
  for (int b=0;b<256;b++){ s1 += p1[b*64]; s2 += p2[b*64]; }
  float lb = 2.f * bdot[i];
  float term = 0.5f * ((logf(s1 - E2) - lb) + (logf(s2 - E2) - lb));
  red[t]=term; __syncthreads();
  for (int st=128; st>0; st>>=1){ if (t<st) red[t]+=red[t+st]; __syncthreads(); }
  if (t==0) atomicAdd(out, red[0] / (float)NROWS);
}

extern "C" void kernel_launch(void* const* d_in, const int* in_sizes, int n_in,
                              void* d_out, int out_size, void* d_ws, size_t ws_size,
                              hipStream_t stream){
  const float* feat1 = (const float*)d_in[0];
  const float* feat2 = (const float*)d_in[1];
  const int*   ei1   = (const int*)d_in[2];
  const float* w1    = (const float*)d_in[3];
  const int*   ei2   = (const int*)d_in[4];
  const float* w2    = (const float*)d_in[5];
  const float* w_l1a = (const float*)d_in[6];
  const float* b_l1a = (const float*)d_in[7];
  const float* w_l1b = (const float*)d_in[8];
  const float* b_l1b = (const float*)d_in[9];
  const float* w_g1  = (const float*)d_in[10];
  const float* b_g1  = (const float*)d_in[11];
  const float* w_g2  = (const float*)d_in[12];
  const float* b_g2  = (const float*)d_in[13];
  const float* w_fc1 = (const float*)d_in[14];
  const float* b_fc1 = (const float*)d_in[15];
  const float* w_fc2 = (const float*)d_in[16];
  const float* b_fc2 = (const float*)d_in[17];

  // P (16.8MB) = ws base; all other live-past-gram buffers start at 17MB.
  // xb/s2/hh are dead before gram3_k but allocated outside P anyway (plenty of ws).
  float* P = (float*)d_ws;
  char* base = (char*)d_ws;
  size_t off = (size_t)17<<20;
  auto alloc = [&](size_t bytes)->void*{
    void* r = base + off;
    off = (off + bytes + 255) & ~(size_t)255;
    return r;
  };
  short* xb   = (short*)alloc((size_t)MROWS*32*2);
  short* s2   = (short*)alloc((size_t)MROWS*128*2);
  short* hh   = (short*)alloc((size_t)MROWS*128*2);
  short* wg1_t  = (short*)alloc(32*256*2);
  short* wg2_t  = (short*)alloc(256*128*2);
  short* wfc1_t = (short*)alloc(128*64*2);
  short* wfc2_t = (short*)alloc(64*128*2);
  unsigned short* Zf = (unsigned short*)alloc((size_t)MROWS*128);   // fragment-order fp8
  int*   deg1 = (int*)alloc(NROWS*4);                               // zeroed pair
  int*   deg2 = (int*)alloc(NROWS*4);
  int* rs1  = (int*)alloc((NROWS+1)*4);
  int* cur1 = (int*)alloc(NROWS*4);
  int* rs2  = (int*)alloc((NROWS+1)*4);
  int* cur2 = (int*)alloc(NROWS*4);
  int*   ecol1 = (int*)alloc((size_t)NEDGE*4);
  float* ewt1  = (float*)alloc((size_t)NEDGE*4);
  int*   ecol2 = (int*)alloc((size_t)NEDGE*4);
  float* ewt2  = (float*)alloc((size_t)NEDGE*4);
  float* bdot  = (float*)alloc(NROWS*4);

  hipMemsetAsync(deg1, 0, (size_t)2*NROWS*4, stream);
  hipMemsetAsync(d_out, 0, sizeof(float), stream);

  WtArgs wa;
  wa.src[0]=w_g1;  wa.dst[0]=wg1_t;  wa.K[0]=32;  wa.N[0]=256;
  wa.src[1]=w_g2;  wa.dst[1]=wg2_t;  wa.K[1]=256; wa.N[1]=128;
  wa.src[2]=w_fc1; wa.dst[2]=wfc1_t; wa.K[2]=128; wa.N[2]=64;
  wa.src[3]=w_fc2; wa.dst[3]=wfc2_t; wa.K[3]=64;  wa.N[3]=128;
  wa.off[0]=0;
  for (int i=0;i<4;i++) wa.off[i+1] = wa.off[i] + wa.K[i]*wa.N[i];
  wa.nwt = (wa.off[4]+255)/256;

  setup2_k<<<wa.nwt + 2*(NEDGE/256) + MROWS/64,256,0,stream>>>(
      wa, ei1, ei2, deg1, deg2, feat1, feat2, w_l1a, b_l1a, w_l1b, b_l1b, xb);
  scan2_k<<<2,256,0,stream>>>(deg1, rs1, cur1, deg2, rs2, cur2);
  fill2_k<<<2*(NEDGE/256),256,0,stream>>>(ei1, w1, cur1, ecol1, ewt1,
                                          ei2, w2, cur2, ecol2, ewt2);

  gg_k<<<MROWS/64,256,0,stream>>>(xb, rs1,ecol1,ewt1, rs2,ecol2,ewt2,
                                  wg1_t, b_g1, wg2_t, s2);
  gather_k<128,false,true><<<MROWS/16,256,0,stream>>>(s2, rs1,ecol1,ewt1,
                                                      rs2,ecol2,ewt2, b_g2, hh);
  pn_k<<<NROWS/32,256,0,stream>>>(hh, wfc1_t, b_fc1, wfc2_t, b_fc2, Zf, bdot);

  gram3_k<<<8224,256,0,stream>>>((const unsigned char*)Zf, P);   // 32896 UT tiles
  rloss_k<<<NROWS/256,256,0,stream>>>(P, bdot, (float*)d_out);
}

// Round 14
// 270.235 us; speedup vs baseline: 1.1067x; 1.1067x over previous
//
#include <hip/hip_runtime.h>
#include <hip/hip_bf16.h>
#include <math.h>

// GRACE-style graph contrastive loss, MI355X (gfx950).
// R14: un-fuse MLP from setup (R13's 3-path setup2_k spilled in the MLP path:
// WRITE_SIZE 17.8MB for 1.4MB of outputs, 67us at 0.6% MFMA). New mlp12_k:
// 512 blocks x 32 rows, WHOLE feat slab staged via LDS with 16 back-to-back
// coalesced float4 loads/thread (fixes row-scattered A-loads: lane stride was
// 2KB = 64 lines/load), conflict-free LDS strides (520/72 shorts -> 4-bank lane
// stride). pn_k: same LDS staging for the paired hh tile. gram3 (53us) untouched.

#define NROWS 8192
#define MROWS 16384
#define NEDGE 262144

typedef __attribute__((ext_vector_type(8))) short bf16x8;
typedef __attribute__((ext_vector_type(4))) float f32x4;
typedef __attribute__((ext_vector_type(2))) float f32x2;
typedef long long i64;

__device__ __forceinline__ short f2bf(float f){
  union { float f; unsigned u; } cv; cv.f = f;
  unsigned u = cv.u;
  unsigned r = (u + 0x7fffu + ((u >> 16) & 1u)) >> 16;  // RNE; inputs finite
  return (short)r;
}
__device__ __forceinline__ f32x4 mfma16(bf16x8 a, bf16x8 b, f32x4 c){
  return __builtin_amdgcn_mfma_f32_16x16x32_bf16(a, b, c, 0, 0, 0);
}
__device__ __forceinline__ float fexp2(float x){
#if __has_builtin(__builtin_amdgcn_exp2f)
  return __builtin_amdgcn_exp2f(x);
#else
  return exp2f(x);
#endif
}

// ---- fp8 e4m3fn pack (RNE) ----
__device__ unsigned char f2e4m3_sw(float f){
  float a = fabsf(f);
  unsigned s = (__float_as_uint(f)>>24)&0x80u;
  if (!(a>0.f)) return (unsigned char)s;
  if (a>448.f) a=448.f;
  int e; frexpf(a,&e);
  int eff=e-1;
  unsigned code;
  if (eff<-6){
    float q=rintf(a*512.f);
    code=(unsigned)q; if(code>7)code=7;
  } else {
    float q=rintf(a*exp2f((float)(3-eff)));
    unsigned mant=(unsigned)q;
    if(mant>=16){mant=8;eff++;}
    if(eff>8) return (unsigned char)(s|0x7e);
    code=((unsigned)(eff+7)<<3)|(mant-8);
  }
  return (unsigned char)(s|code);
}
__device__ __forceinline__ unsigned short pack2fp8(float a, float b){
#if __has_builtin(__builtin_amdgcn_cvt_pk_fp8_f32)
  int v = __builtin_amdgcn_cvt_pk_fp8_f32(a, b, 0, false);
  return (unsigned short)(v & 0xffff);
#else
  return (unsigned short)((unsigned)f2e4m3_sw(a) | ((unsigned)f2e4m3_sw(b)<<8));
#endif
}

// ---- setup: weight transpose+bf16 (6 weights) | degree histogram ----
struct WtArgs {
  const float* src[6];
  short* dst[6];
  int K[6], N[6];
  int off[7];
  int nwt;
};
__global__ void setup_k(WtArgs a, const int* __restrict__ ei1, const int* __restrict__ ei2,
                        int* __restrict__ deg1, int* __restrict__ deg2){
  int b = blockIdx.x;
  if (b < a.nwt){
    int i = b*256 + threadIdx.x;
    if (i >= a.off[6]) return;
    int s = 0;
    #pragma unroll
    for (int j=1;j<6;j++) if (i >= a.off[j]) s=j;
    int l = i - a.off[s];
    int K=a.K[s], N=a.N[s];
    int k=l/N, n=l-k*N;
    a.dst[s][(long)n*K+k] = f2bf(a.src[s][l]);
  } else {
    int hb = b - a.nwt;
    const int* ei = (hb < NEDGE/256) ? ei1 : ei2;
    int* deg = (hb < NEDGE/256) ? deg1 : deg2;
    int e = (hb % (NEDGE/256))*256 + threadIdx.x;
    atomicAdd(&deg[ei[e]], 1);
  }
}

// ---- mlp12 v2: xb[M,32] = (relu(feat@Wa+ba))@Wb+bb. 512 blocks x 32 rows.
// Whole 32x512 feat slab -> LDS (coalesced, 16 float4/thread, one wait), then
// pure-LDS MFMA. LDS strides 520/72 shorts = conflict-free fragment reads.
__global__ __launch_bounds__(256) void mlp12_k(const float* __restrict__ F0, const float* __restrict__ F1,
                                               const short* __restrict__ Wa, const float* __restrict__ ba,
                                               const short* __restrict__ Wb, const float* __restrict__ bb,
                                               short* __restrict__ xb){
  __shared__ short As[32*520];   // 32x512 bf16, +8 pad
  __shared__ short a1s[32*72];   // 32x64 bf16, +8 pad
  const int tid = threadIdx.x;
  const int m0 = blockIdx.x*32;
  const float* F = (m0 < NROWS) ? (F0 + (long)m0*512) : (F1 + (long)(m0-NROWS)*512);
  {
    float4 st[16];
    #pragma unroll
    for (int i=0;i<16;i++) st[i] = *(const float4*)(F + (long)(i*256+tid)*4);
    #pragma unroll
    for (int i=0;i<16;i++){
      int idx = i*256+tid, row = idx>>7, c4 = idx&127;
      unsigned lo = (unsigned)(unsigned short)f2bf(st[i].x) | ((unsigned)(unsigned short)f2bf(st[i].y)<<16);
      unsigned hi = (unsigned)(unsigned short)f2bf(st[i].z) | ((unsigned)(unsigned short)f2bf(st[i].w)<<16);
      uint2 o = {lo, hi};
      *(uint2*)&As[row*520 + c4*4] = o;
    }
  }
  __syncthreads();
  const int wave = tid>>6, lane = tid&63, quad = lane>>4, cl = lane&15;
  f32x4 zero = {0.f,0.f,0.f,0.f};
  {
    // stage1: 32 rows (MT=2) x 16 cols per wave, K=512
    const int wno = wave*16;
    f32x4 acc[2] = {zero, zero};
    #pragma unroll
    for (int kc=0;kc<16;kc++){
      const int ko = kc*32 + quad*8;
      bf16x8 a0 = *(const bf16x8*)&As[(cl)*520 + ko];
      bf16x8 a1 = *(const bf16x8*)&As[(16+cl)*520 + ko];
      bf16x8 b = *(const bf16x8*)(Wa + (long)(wno + cl)*512 + ko);
      acc[0] = mfma16(a0, b, acc[0]);
      acc[1] = mfma16(a1, b, acc[1]);
    }
    int col = wno + cl;
    float bv = ba[col];
    #pragma unroll
    for (int mt=0;mt<2;mt++)
      #pragma unroll
      for (int r=0;r<4;r++)
        a1s[(mt*16 + quad*4 + r)*72 + col] = f2bf(fmaxf(acc[mt][r] + bv, 0.f));
  }
  __syncthreads();
  if (wave < 2){
    // stage2: wave w -> rows w*16..+15, full 32 cols (NT=2), K=64
    f32x4 acc2[2] = {zero, zero};
    #pragma unroll
    for (int kc=0;kc<2;kc++){
      const int ko = kc*32 + quad*8;
      bf16x8 a = *(const bf16x8*)&a1s[(wave*16+cl)*72 + ko];
      #pragma unroll
      for (int nt=0;nt<2;nt++){
        bf16x8 b = *(const bf16x8*)(Wb + (long)(nt*16 + cl)*64 + ko);
        acc2[nt] = mfma16(a, b, acc2[nt]);
      }
    }
    #pragma unroll
    for (int nt=0;nt<2;nt++){
      int col = nt*16 + cl;
      float bv = bb[col];
      #pragma unroll
      for (int r=0;r<4;r++)
        xb[(long)(m0 + wave*16 + quad*4 + r)*32 + col] = f2bf(acc2[nt][r] + bv);
    }
  }
}

// ---- CSR build ----
__global__ void scan2_k(const int* __restrict__ deg1, int* __restrict__ rs1, int* __restrict__ cur1,
                        const int* __restrict__ deg2, int* __restrict__ rs2, int* __restrict__ cur2){
  const int* deg = blockIdx.x ? deg2 : deg1;
  int* rowstart = blockIdx.x ? rs2 : rs1;
  int* cursor = blockIdx.x ? cur2 : cur1;
  __shared__ int csum[256];
  __shared__ int base[257];
  int t = threadIdx.x;
  int loc[32];
  int s = 0;
  for (int j=0;j<32;j++){ int d = deg[t*32+j]; loc[j] = s; s += d; }
  csum[t] = s;
  __syncthreads();
  if (t==0){ int a=0; for (int i=0;i<256;i++){ base[i]=a; a+=csum[i]; } base[256]=a; }
  __syncthreads();
  for (int j=0;j<32;j++){ int v = base[t] + loc[j]; rowstart[t*32+j]=v; cursor[t*32+j]=v; }
  if (t==0) rowstart[NROWS] = base[256];
}
__global__ void fill2_k(const int* __restrict__ ei1, const float* __restrict__ w1, int* __restrict__ cur1,
                        int* __restrict__ ecol1, float* __restrict__ ew1,
                        const int* __restrict__ ei2, const float* __restrict__ w2, int* __restrict__ cur2,
                        int* __restrict__ ecol2, float* __restrict__ ew2){
  int b = blockIdx.x;
  bool g2 = (b >= NEDGE/256);
  const int* ei = g2 ? ei2 : ei1;
  const float* w = g2 ? w2 : w1;
  int* cursor = g2 ? cur2 : cur1;
  int* ecol = g2 ? ecol2 : ecol1;
  float* ew = g2 ? ew2 : ew1;
  int e = (b % (NEDGE/256))*256 + threadIdx.x;
  int r = ei[e];
  int p = atomicAdd(&cursor[r], 1);
  ecol[p] = ei[NEDGE + e];
  ew[p] = w[e];
}

// ---- gather helpers ----
__device__ __forceinline__ void acc8(float* acc, int4 v, float f){
  const unsigned* u = (const unsigned*)&v;
  #pragma unroll
  for (int i=0;i<4;i++){
    union{unsigned x; float y;} lo, hi;
    lo.x = u[i] << 16;
    hi.x = u[i] & 0xffff0000u;
    acc[2*i]   = fmaf(f, lo.y, acc[2*i]);
    acc[2*i+1] = fmaf(f, hi.y, acc[2*i+1]);
  }
}
template<int C>
__device__ __forceinline__ void gather_row(float* acc, const short* sb,
                                           const int* ec, const float* w, int s, int e){
  int k = s;
  for (; k+16 <= e; k+=16){
    int c[16]; float f[16]; int4 v[16];
    #pragma unroll
    for (int u=0;u<16;u++){ c[u]=ec[k+u]; f[u]=w[k+u]; }
    #pragma unroll
    for (int u=0;u<16;u++) v[u] = *(const int4*)(sb + (long)c[u]*C);
    #pragma unroll
    for (int u=0;u<16;u++) acc8(acc, v[u], f[u]);
  }
  for (; k+4 <= e; k+=4){
    int c0=ec[k],c1=ec[k+1],c2=ec[k+2],c3=ec[k+3];
    float f0=w[k],f1=w[k+1],f2=w[k+2],f3=w[k+3];
    int4 v0 = *(const int4*)(sb + (long)c0*C);
    int4 v1 = *(const int4*)(sb + (long)c1*C);
    int4 v2 = *(const int4*)(sb + (long)c2*C);
    int4 v3 = *(const int4*)(sb + (long)c3*C);
    acc8(acc,v0,f0); acc8(acc,v1,f1); acc8(acc,v2,f2); acc8(acc,v3,f3);
  }
  for (; k < e; k++){
    int4 v0 = *(const int4*)(sb + (long)ec[k]*C);
    acc8(acc,v0,w[k]);
  }
}

// ---- standalone gather (layer-2 aggregation, C=128, bias) ----
template<int C, bool RELU, bool HASB>
__global__ __launch_bounds__(256) void gather_k(const short* __restrict__ sup,
    const int* __restrict__ rs1, const int* __restrict__ ec1, const float* __restrict__ w1,
    const int* __restrict__ rs2, const int* __restrict__ ec2, const float* __restrict__ w2,
    const float* __restrict__ bias, short* __restrict__ out){
  constexpr int G = C/8;
  const int g = threadIdx.x % G;
  const int sub = threadIdx.x / G;
  const int row = blockIdx.x*(256/G) + sub;
  const int* rs; const int* ec; const float* w; int soff, lr;
  if (row < NROWS){ rs=rs1; ec=ec1; w=w1; soff=0; lr=row; }
  else            { rs=rs2; ec=ec2; w=w2; soff=NROWS; lr=row-NROWS; }
  const short* sb = sup + (long)soff*C + g*8;
  float acc[8];
  #pragma unroll
  for (int j=0;j<8;j++) acc[j] = HASB ? bias[g*8+j] : 0.f;
  gather_row<C>(acc, sb, ec, w, rs[lr], rs[lr+1]);
  int4 ov;
  unsigned* ou = (unsigned*)&ov;
  #pragma unroll
  for (int i=0;i<4;i++){
    float a0 = acc[2*i], a1 = acc[2*i+1];
    if (RELU){ a0 = fmaxf(a0,0.f); a1 = fmaxf(a1,0.f); }
    ou[i] = (unsigned)(unsigned short)f2bf(a0) | ((unsigned)(unsigned short)f2bf(a1)<<16);
  }
  *(int4*)(out + (long)row*C + g*8) = ov;
}

// ---- gg_k: gather32 (adj@xb -> LDS) + g34 (relu(ax@Wg1+bg1)@Wg2 -> s2) ----
__global__ __launch_bounds__(256) void gg_k(const short* __restrict__ xb,
    const int* __restrict__ rs1, const int* __restrict__ ec1, const float* __restrict__ w1,
    const int* __restrict__ rs2, const int* __restrict__ ec2, const float* __restrict__ w2,
    const short* __restrict__ Wg1, const float* __restrict__ bg1,
    const short* __restrict__ Wg2, short* __restrict__ s2){
  __shared__ short axs[64*40];    // gathered ax tile (pad 8)
  __shared__ short hbs[64*264];   // relu(ax@Wg1+b) tile (pad 8)
  const int tid = threadIdx.x;
  const int m0 = blockIdx.x*64;
  {
    const int g = tid & 3, sub = tid >> 2;
    const int row = m0 + sub;
    const int* rs; const int* ec; const float* w; int soff, lr;
    if (row < NROWS){ rs=rs1; ec=ec1; w=w1; soff=0; lr=row; }
    else            { rs=rs2; ec=ec2; w=w2; soff=NROWS; lr=row-NROWS; }
    const short* sb = xb + (long)soff*32 + g*8;
    float acc[8];
    #pragma unroll
    for (int j=0;j<8;j++) acc[j] = 0.f;
    gather_row<32>(acc, sb, ec, w, rs[lr], rs[lr+1]);
    int4 ov;
    unsigned* ou = (unsigned*)&ov;
    #pragma unroll
    for (int i=0;i<4;i++)
      ou[i] = (unsigned)(unsigned short)f2bf(acc[2*i]) | ((unsigned)(unsigned short)f2bf(acc[2*i+1])<<16);
    *(int4*)&axs[sub*40 + g*8] = ov;
  }
  __syncthreads();
  const int wave = tid>>6, lane = tid&63, quad = lane>>4, cl = lane&15;
  f32x4 zero = {0.f,0.f,0.f,0.f};
  {
    const int wno = wave*64;
    f32x4 acc[4][4];
    #pragma unroll
    for (int i=0;i<4;i++)
      #pragma unroll
      for (int j=0;j<4;j++) acc[i][j]=zero;
    const int ko = quad*8;
    bf16x8 a[4], b[4];
    #pragma unroll
    for (int mt=0;mt<4;mt++)
      a[mt] = *(const bf16x8*)&axs[(mt*16+cl)*40 + ko];
    #pragma unroll
    for (int nt=0;nt<4;nt++)
      b[nt] = *(const bf16x8*)(Wg1 + (long)(wno + nt*16 + cl)*32 + ko);
    #pragma unroll
    for (int mt=0;mt<4;mt++)
      #pragma unroll
      for (int nt=0;nt<4;nt++)
        acc[mt][nt] = mfma16(a[mt], b[nt], acc[mt][nt]);
    #pragma unroll
    for (int nt=0;nt<4;nt++){
      int col = wno + nt*16 + cl;
      float bv = bg1[col];
      #pragma unroll
      for (int mt=0;mt<4;mt++)
        #pragma unroll
        for (int r=0;r<4;r++)
          hbs[(mt*16 + quad*4 + r)*264 + col] = f2bf(fmaxf(acc[mt][nt][r] + bv, 0.f));
    }
  }
  __syncthreads();
  {
    const int wno = wave*32;
    f32x4 acc[4][2];
    #pragma unroll
    for (int i=0;i<4;i++){ acc[i][0]=zero; acc[i][1]=zero; }
    #pragma unroll
    for (int kc=0;kc<8;kc++){
      const int ko = kc*32 + quad*8;
      bf16x8 a[4], b[2];
      #pragma unroll
      for (int mt=0;mt<4;mt++)
        a[mt] = *(const bf16x8*)&hbs[(mt*16+cl)*264 + ko];
      #pragma unroll
      for (int nt=0;nt<2;nt++)
        b[nt] = *(const bf16x8*)(Wg2 + (long)(wno + nt*16 + cl)*256 + ko);
      #pragma unroll
      for (int mt=0;mt<4;mt++)
        #pragma unroll
        for (int nt=0;nt<2;nt++)
          acc[mt][nt] = mfma16(a[mt], b[nt], acc[mt][nt]);
    }
    #pragma unroll
    for (int mt=0;mt<4;mt++)
      #pragma unroll
      for (int nt=0;nt<2;nt++){
        int col = wno + nt*16 + cl;
        #pragma unroll
        for (int r=0;r<4;r++)
          s2[(long)(m0 + mt*16 + quad*4 + r)*128 + col] = f2bf(acc[mt][nt][r]);
      }
  }
}

// ---- pn_k: proj1(elu) + proj2 + normalize + fp8-quantize, PAIR-ROW blocks.
// hh tile (paired 32+32 rows x 128) staged via LDS with coalesced loads.
__global__ __launch_bounds__(256) void pn_k(const short* __restrict__ hh,
    const short* __restrict__ Wf1, const float* __restrict__ bf1,
    const short* __restrict__ Wf2, const float* __restrict__ bf2,
    unsigned short* __restrict__ Zf, float* __restrict__ bdot){
  __shared__ short hs[64*136];
  __shared__ short t2s[64*72];
  __shared__ float zs[64*132];
  __shared__ float sp[4][64];
  __shared__ float dp[4][32];
  __shared__ float rnS[64];
  const float SQKE = 1.6986436f;   // sqrt(2*log2(e))
  const int tid = threadIdx.x;
  const int wave = tid>>6, lane = tid&63, quad = lane>>4, cl = lane&15;
  const int m0h = blockIdx.x*32;
  {
    // stage hh: region1 rows m0h..+31 -> hs rows 0..31; region2 -> rows 32..63
    const short* r1 = hh + (long)m0h*128;
    const short* r2 = hh + (long)(NROWS + m0h)*128;
    #pragma unroll
    for (int i=0;i<2;i++){
      int idx = i*256 + tid;              // int4 index into 32x128-short region
      int row = idx >> 4, c16 = idx & 15;
      *(int4*)&hs[row*136 + c16*8] = *(const int4*)(r1 + row*128 + c16*8);
      *(int4*)&hs[(32+row)*136 + c16*8] = *(const int4*)(r2 + row*128 + c16*8);
    }
  }
  __syncthreads();
  f32x4 zero = {0.f,0.f,0.f,0.f};
  {
    // proj1: NN=64, K=128, elu -> t2s
    const int wno = wave*16;
    f32x4 acc[4];
    #pragma unroll
    for (int i=0;i<4;i++) acc[i]=zero;
    #pragma unroll
    for (int kc=0;kc<4;kc++){
      const int ko = kc*32 + quad*8;
      bf16x8 a[4], b;
      #pragma unroll
      for (int mt=0;mt<4;mt++)
        a[mt] = *(const bf16x8*)&hs[(mt*16+cl)*136 + ko];
      b = *(const bf16x8*)(Wf1 + (long)(wno + cl)*128 + ko);
      #pragma unroll
      for (int mt=0;mt<4;mt++) acc[mt] = mfma16(a[mt], b, acc[mt]);
    }
    int col = wno + cl;
    float bv = bf1[col];
    #pragma unroll
    for (int mt=0;mt<4;mt++)
      #pragma unroll
      for (int r=0;r<4;r++){
        float v = acc[mt][r] + bv;
        v = (v > 0.f) ? v : expm1f(v);
        t2s[(mt*16 + quad*4 + r)*72 + col] = f2bf(v);
      }
  }
  __syncthreads();
  {
    // proj2: NN=128, K=64 -> zs (fp32)
    const int wno = wave*32;
    f32x4 acc[4][2];
    #pragma unroll
    for (int i=0;i<4;i++){ acc[i][0]=zero; acc[i][1]=zero; }
    #pragma unroll
    for (int kc=0;kc<2;kc++){
      const int ko = kc*32 + quad*8;
      bf16x8 a[4], b[2];
      #pragma unroll
      for (int mt=0;mt<4;mt++)
        a[mt] = *(const bf16x8*)&t2s[(mt*16+cl)*72 + ko];
      #pragma unroll
      for (int nt=0;nt<2;nt++)
        b[nt] = *(const bf16x8*)(Wf2 + (long)(wno + nt*16 + cl)*64 + ko);
      #pragma unroll
      for (int mt=0;mt<4;mt++)
        #pragma unroll
        for (int nt=0;nt<2;nt++)
          acc[mt][nt] = mfma16(a[mt], b[nt], acc[mt][nt]);
    }
    #pragma unroll
    for (int mt=0;mt<4;mt++)
      #pragma unroll
      for (int nt=0;nt<2;nt++){
        int col = wno + nt*16 + cl;
        float bv = bf2[col];
        #pragma unroll
        for (int r=0;r<4;r++)
          zs[(mt*16 + quad*4 + r)*132 + col] = acc[mt][nt][r] + bv;
      }
  }
  __syncthreads();
  {
    int row = tid & 63, qtr = tid >> 6;
    const float* zr = &zs[row*132 + qtr*32];
    float s = 0.f;
    #pragma unroll 8
    for (int c=0;c<32;c++) s += zr[c]*zr[c];
    sp[qtr][row] = s;
    if (row < 32){
      const float* zb_ = &zs[(row+32)*132 + qtr*32];
      float d = 0.f;
      #pragma unroll 8
      for (int c=0;c<32;c++) d += zr[c]*zb_[c];
      dp[qtr][row] = d;
    }
  }
  __syncthreads();
  if (tid < 64){
    float ssq = sp[0][tid]+sp[1][tid]+sp[2][tid]+sp[3][tid];
    rnS[tid] = 1.f / fmaxf(sqrtf(ssq), 1e-12f);
  }
  __syncthreads();
  if (tid < 32){
    float dot = dp[0][tid]+dp[1][tid]+dp[2][tid]+dp[3][tid];
    bdot[m0h + tid] = dot * rnS[tid] * rnS[tid+32];
  }
  {
    // fp8*sqrt(KE) quantize into MFMA-fragment-order Zf
    int lr = tid >> 2;
    int grow = (lr < 32) ? (m0h + lr) : (NROWS + m0h + lr - 32);
    float s = rnS[lr] * SQKE;
    int p0 = (tid & 3)*16;
    #pragma unroll
    for (int pp=0;pp<16;pp++){
      int p = p0 + pp;
      int d = p>>1, h = p&1, kc = d>>3, q = (d>>1)&3, j4 = d&1;
      long o = ((long)(grow>>4)*512 + kc*128 + j4 + ((grow&15)+16*q)*2)*2 + h;
      Zf[o] = pack2fp8(zs[lr*132 + 2*p]*s, zs[lr*132 + 2*p + 1]*s);
    }
  }
}

// ---- LDS-free symmetric exp-Gram partials (proven 53us; do not touch).
__global__ __launch_bounds__(256,4) void gram3_k(const unsigned char* __restrict__ Zf,
                                                 float* __restrict__ P){
  __shared__ float srow[4][64];
  __shared__ float scol[4][64];
  const int wave = threadIdx.x>>6, lane = threadIdx.x&63;
  const int t = blockIdx.x*4 + wave;           // UT tile index, T=256
  int ti = (int)((513.0f - sqrtf(513.0f*513.0f - 8.0f*(float)t))*0.5f);
  while ((ti+1)*256 - ((ti+1)*ti)/2 <= t) ti++;
  while (ti*256 - (ti*(ti-1))/2 > t) ti--;
  const int tj = ti + (t - (ti*256 - (ti*(ti-1))/2));
  const unsigned char* za = Zf + (long)ti*16*512 + lane*8;
  const unsigned char* zb = Zf + (long)tj*16*512 + lane*8;

  f32x4 zero = {0.f,0.f,0.f,0.f};
  f32x4 acc[4][4];
  #pragma unroll
  for (int i=0;i<4;i++)
    #pragma unroll
    for (int j=0;j<4;j++) acc[i][j]=zero;

  i64 aA[4], bA[4], aB[4], bB[4];
  #pragma unroll
  for (int x=0;x<4;x++){
    aA[x] = *(const i64*)(za + (x*4+0)*512);
    bA[x] = *(const i64*)(zb + (x*4+0)*512);
  }
  #pragma unroll
  for (int kc=0;kc<4;kc++){
    i64* ac = (kc&1) ? aB : aA;
    i64* bc = (kc&1) ? bB : bA;
    i64* an = (kc&1) ? aA : aB;
    i64* bn = (kc&1) ? bA : bB;
    if (kc<3){
      #pragma unroll
      for (int x=0;x<4;x++){
        an[x] = *(const i64*)(za + (x*4+kc+1)*512);
        bn[x] = *(const i64*)(zb + (x*4+kc+1)*512);
      }
    }
    #pragma unroll
    for (int mt=0;mt<4;mt++)
      #pragma unroll
      for (int nt=0;nt<4;nt++)
        acc[mt][nt] = __builtin_amdgcn_mfma_f32_16x16x32_fp8_fp8(ac[mt], bc[nt], acc[mt][nt], 0, 0, 0);
  }

  const int quad = lane>>4, cl = lane&15;
  f32x2 z2 = {0.f,0.f};
  f32x2 rs01[4] = {z2,z2,z2,z2}, rs23[4] = {z2,z2,z2,z2};
  f32x2 cs[4] = {z2,z2,z2,z2};
  #pragma unroll
  for (int mt=0;mt<4;mt++){
    #pragma unroll
    for (int nt=0;nt<4;nt++){
      f32x4 v = acc[mt][nt];
      float e0 = fexp2(v[0]), e1 = fexp2(v[1]);
      float e2 = fexp2(v[2]), e3 = fexp2(v[3]);
      f32x2 p01 = {e0,e1}, p23 = {e2,e3};
      rs01[mt] += p01; rs23[mt] += p23;
      cs[nt] += p01; cs[nt] += p23;
    }
  }
  #pragma unroll
  for (int mt=0;mt<4;mt++){
    union{f32x2 v; double d;} u0, u1;
    u0.v = rs01[mt]; u1.v = rs23[mt];
    #pragma unroll
    for (int m=1;m<16;m<<=1){
      union{double d; f32x2 v;} o0, o1;
      o0.d = __shfl_xor(u0.d, m); o1.d = __shfl_xor(u1.d, m);
      u0.v += o0.v; u1.v += o1.v;
    }
    if (cl==0){
      f32x4 rv = {u0.v.x, u0.v.y, u1.v.x, u1.v.y};
      *(f32x4*)&srow[wave][mt*16 + quad*4] = rv;
    }
  }
  __threadfence_block();
  P[((long)ti*256 + tj)*64 + lane] = srow[wave][lane];
  if (ti != tj){
    #pragma unroll
    for (int nt=0;nt<4;nt++){
      float s = cs[nt].x + cs[nt].y;
      s += __shfl_xor(s,16); s += __shfl_xor(s,32);
      if (quad==0) scol[wave][nt*16 + cl] = s;
    }
    __threadfence_block();
    P[((long)tj*256 + ti)*64 + lane] = scol[wave][lane];
  }
}

// ---- fused final reduce + loss ----
__global__ void rloss_k(const float* __restrict__ P, const float* __restrict__ bdot,
                        float* __restrict__ out){
  __shared__ float red[256];
  const float E2 = 7.3890560989306495f;  // exp(2) = diag(refl)
  int t = threadIdx.x;
  int i = blockIdx.x*256 + t;            // 0..8191
  int j = i + NROWS;
  const float* p1 = P + (long)(i>>6)*256*64 + (i&63);
  const float* p2 = P + (long)(j>>6)*256*64 + (j&63);
  float s1 = 0.f, s2 = 0.f;
  #pragma unroll 8
  for (int b=0;b<256;b++){ s1 += p1[b*64]; s2 += p2[b*64]; }
  float lb = 2.f * bdot[i];
  float term = 0.5f * ((logf(s1 - E2) - lb) + (logf(s2 - E2) - lb));
  red[t]=term; __syncthreads();
  for (int st=128; st>0; st>>=1){ if (t<st) red[t]+=red[t+st]; __syncthreads(); }
  if (t==0) atomicAdd(out, red[0] / (float)NROWS);
}

extern "C" void kernel_launch(void* const* d_in, const int* in_sizes, int n_in,
                              void* d_out, int out_size, void* d_ws, size_t ws_size,
                              hipStream_t stream){
  const float* feat1 = (const float*)d_in[0];
  const float* feat2 = (const float*)d_in[1];
  const int*   ei1   = (const int*)d_in[2];
  const float* w1    = (const float*)d_in[3];
  const int*   ei2   = (const int*)d_in[4];
  const float* w2    = (const float*)d_in[5];
  const float* w_l1a = (const float*)d_in[6];
  const float* b_l1a = (const float*)d_in[7];
  const float* w_l1b = (const float*)d_in[8];
  const float* b_l1b = (const float*)d_in[9];
  const float* w_g1  = (const float*)d_in[10];
  const float* b_g1  = (const float*)d_in[11];
  const float* w_g2  = (const float*)d_in[12];
  const float* b_g2  = (const float*)d_in[13];
  const float* w_fc1 = (const float*)d_in[14];
  const float* b_fc1 = (const float*)d_in[15];
  const float* w_fc2 = (const float*)d_in[16];
  const float* b_fc2 = (const float*)d_in[17];

  float* P = (float*)d_ws;          // 16.8MB partials at ws base
  char* base = (char*)d_ws;
  size_t off = (size_t)17<<20;      // live buffers beyond P
  auto alloc = [&](size_t bytes)->void*{
    void* r = base + off;
    off = (off + bytes + 255) & ~(size_t)255;
    return r;
  };
  short* xb   = (short*)alloc((size_t)MROWS*32*2);
  short* s2   = (short*)alloc((size_t)MROWS*128*2);
  short* hh   = (short*)alloc((size_t)MROWS*128*2);
  short* wl1a_t = (short*)alloc(512*64*2);
  short* wl1b_t = (short*)alloc(64*32*2);
  short* wg1_t  = (short*)alloc(32*256*2);
  short* wg2_t  = (short*)alloc(256*128*2);
  short* wfc1_t = (short*)alloc(128*64*2);
  short* wfc2_t = (short*)alloc(64*128*2);
  unsigned short* Zf = (unsigned short*)alloc((size_t)MROWS*128);   // fragment-order fp8
  int*   deg1 = (int*)alloc(NROWS*4);                               // zeroed pair
  int*   deg2 = (int*)alloc(NROWS*4);
  int* rs1  = (int*)alloc((NROWS+1)*4);
  int* cur1 = (int*)alloc(NROWS*4);
  int* rs2  = (int*)alloc((NROWS+1)*4);
  int* cur2 = (int*)alloc(NROWS*4);
  int*   ecol1 = (int*)alloc((size_t)NEDGE*4);
  float* ewt1  = (float*)alloc((size_t)NEDGE*4);
  int*   ecol2 = (int*)alloc((size_t)NEDGE*4);
  float* ewt2  = (float*)alloc((size_t)NEDGE*4);
  float* bdot  = (float*)alloc(NROWS*4);

  hipMemsetAsync(deg1, 0, (size_t)2*NROWS*4, stream);
  hipMemsetAsync(d_out, 0, sizeof(float), stream);

  WtArgs wa;
  wa.src[0]=w_l1a; wa.dst[0]=wl1a_t; wa.K[0]=512; wa.N[0]=64;
  wa.src[1]=w_l1b; wa.dst[1]=wl1b_t; wa.K[1]=64;  wa.N[1]=32;
  wa.src[2]=w_g1;  wa.dst[2]=wg1_t;  wa.K[2]=32;  wa.N[2]=256;
  wa.src[3]=w_g2;  wa.dst[3]=wg2_t;  wa.K[3]=256; wa.N[3]=128;
  wa.src[4]=w_fc1; wa.dst[4]=wfc1_t; wa.K[4]=128; wa.N[4]=64;
  wa.src[5]=w_fc2; wa.dst[5]=wfc2_t; wa.K[5]=64;  wa.N[5]=128;
  wa.off[0]=0;
  for (int i=0;i<6;i++) wa.off[i+1] = wa.off[i] + wa.K[i]*wa.N[i];
  wa.nwt = (wa.off[6]+255)/256;

  setup_k<<<wa.nwt + 2*(NEDGE/256),256,0,stream>>>(wa, ei1, ei2, deg1, deg2);
  scan2_k<<<2,256,0,stream>>>(deg1, rs1, cur1, deg2, rs2, cur2);
  fill2_k<<<2*(NEDGE/256),256,0,stream>>>(ei1, w1, cur1, ecol1, ewt1,
                                          ei2, w2, cur2, ecol2, ewt2);

  mlp12_k<<<MROWS/32,256,0,stream>>>(feat1, feat2, wl1a_t, b_l1a, wl1b_t, b_l1b, xb);
  gg_k<<<MROWS/64,256,0,stream>>>(xb, rs1,ecol1,ewt1, rs2,ecol2,ewt2,
                                  wg1_t, b_g1, wg2_t, s2);
  gather_k<128,false,true><<<MROWS/16,256,0,stream>>>(s2, rs1,ecol1,ewt1,
                                                      rs2,ecol2,ewt2, b_g2, hh);
  pn_k<<<NROWS/32,256,0,stream>>>(hh, wfc1_t, b_fc1, wfc2_t, b_fc2, Zf, bdot);

  gram3_k<<<8224,256,0,stream>>>((const unsigned char*)Zf, P);   // 32896 UT tiles
  rloss_k<<<NROWS/256,256,0,stream>>>(P, bdot, (float*)d_out);
}